// Round 11
// baseline (421.675 us; speedup 1.0000x reference)
//
#include <hip/hip_runtime.h>
#include <hip/hip_bf16.h>
#include <math.h>

#define IN_DIM 512
#define HID    1024
#define NE     16
#define T_TOK  8192
#define NPAIR  (T_TOK*2)

typedef __attribute__((ext_vector_type(8))) short bf16x8;
typedef __attribute__((ext_vector_type(8))) unsigned short ushort8;
typedef __attribute__((ext_vector_type(4))) float f32x4;

__device__ __forceinline__ unsigned short f2b(float f){
  unsigned u = __float_as_uint(f);
  u += 0x7FFF + ((u >> 16) & 1);           // round-to-nearest-even
  return (unsigned short)(u >> 16);
}
__device__ __forceinline__ float b2f(unsigned short u){
  return __uint_as_float(((unsigned)u) << 16);
}

// Barrier WITHOUT the vmcnt(0) drain __syncthreads() forces (R6-verified pattern).
__device__ __forceinline__ void barrier_lds_only(){
  asm volatile("s_waitcnt lgkmcnt(0)" ::: "memory");
  __builtin_amdgcn_s_barrier();
}

// ---------------- fused head (R13/R18 verbatim, 52-60us proven): router + tconv ----
// router blocks [0,2048): one wave per token, shuffle-butterfly reduce.
// tconv W1: blocks [2048,4096): [E][512][1024] f32 -> [E][1024][512] bf16
// tconv W2: blocks [4096,6144): [E][1024][512] f32 -> [E][512][1024] bf16
// (R17: no global hot atomics; R16: no spin barriers; R19: no atomic epilogues.)
__global__ __launch_bounds__(256) void fused_head(
    const float* __restrict__ x, const float* __restrict__ Wr, const float* __restrict__ br,
    unsigned short* __restrict__ xb, int* __restrict__ eid, float* __restrict__ pw,
    const float* __restrict__ W1, unsigned short* __restrict__ O1,
    const float* __restrict__ W2, unsigned short* __restrict__ O2)
{
  __shared__ float tile[64][65];
  const int b = blockIdx.x;
  const int tid = threadIdx.x;

  if (b < 2048){
    int wid = tid >> 6, lane = tid & 63;
    int t = b*4 + wid;
    const float4* xr4 = (const float4*)(x + (size_t)t*IN_DIM);
    ushort4*      xb4 = (ushort4*)(xb + (size_t)t*IN_DIM);

    float acc[NE];
    #pragma unroll
    for (int i=0;i<NE;i++) acc[i]=0.f;

    #pragma unroll
    for (int j=0;j<2;j++){
      int f = j*64 + lane;
      float4 v = xr4[f];
      ushort4 o; o.x=f2b(v.x); o.y=f2b(v.y); o.z=f2b(v.z); o.w=f2b(v.w);
      xb4[f] = o;
      const float4* wr4 = (const float4*)(Wr + (size_t)(f*4)*NE);
      const float* vv = (const float*)&v;
      #pragma unroll
      for (int rr=0; rr<4; rr++){
        float xv = vv[rr];
        #pragma unroll
        for (int q=0;q<4;q++){
          float4 w = wr4[rr*4+q];
          acc[q*4+0] += xv*w.x; acc[q*4+1] += xv*w.y;
          acc[q*4+2] += xv*w.z; acc[q*4+3] += xv*w.w;
        }
      }
    }
    #pragma unroll
    for (int off=32; off>=1; off>>=1){
      #pragma unroll
      for (int i=0;i<NE;i++) acc[i] += __shfl_xor(acc[i], off, 64);
    }
    if (lane==0){
      #pragma unroll
      for (int i=0;i<NE;i++) acc[i] += br[i];
      int e0=0; float l0=acc[0];
      #pragma unroll
      for (int i=1;i<NE;i++) if (acc[i] > l0){ l0=acc[i]; e0=i; }
      int e1=-1; float l1=-3.0e38f;
      #pragma unroll
      for (int i=0;i<NE;i++) if (i!=e0 && acc[i] > l1){ l1=acc[i]; e1=i; }
      float w0 = 1.f/(1.f + __expf(l1 - l0));
      float w1 = 1.f - w0;
      pw[t*2+0] = w0; pw[t*2+1] = w1;
      eid[t*2+0] = e0; eid[t*2+1] = e1;
    }
    return;
  }

  // ---- tconv 64x64 ----
  const float* src; unsigned short* dst; int M, N, m0, n0;
  const int bb = b - 2048;
  if (bb < 2048){
    M = IN_DIM; N = HID;
    int e = bb >> 7, r = bb & 127;            // 8 m-tiles x 16 n-tiles
    n0 = (r & 15)*64; m0 = (r >> 4)*64;
    src = W1 + (size_t)e*M*N; dst = O1 + (size_t)e*M*N;
  } else {
    int b2 = bb - 2048; M = HID; N = IN_DIM;
    int e = b2 >> 7, r = b2 & 127;            // 16 m-tiles x 8 n-tiles
    n0 = (r & 7)*64; m0 = (r >> 3)*64;
    src = W2 + (size_t)e*M*N; dst = O2 + (size_t)e*M*N;
  }
  const int lr = tid >> 4, lc = (tid & 15)*4;
  #pragma unroll
  for (int i=0;i<4;i++)
    *(float4*)&tile[lr + i*16][lc] = *(const float4*)&src[(size_t)(m0 + lr + i*16)*N + n0 + lc];
  __syncthreads();
  const int nr = tid >> 3, mc = (tid & 7)*8;
  #pragma unroll
  for (int p=0;p<2;p++){
    int n = nr + p*32;
    ushort8 o;
    #pragma unroll
    for (int j=0;j<8;j++) o[j] = f2b(tile[mc+j][n]);
    *(ushort8*)&dst[(size_t)(n0 + n)*M + m0 + mc] = o;
  }
}

// ---------------- PERSISTENT grouped GEMM with SELF-BUCKETING -----------------------
// R20: bucket_kernel deleted. Each block recomputes, from eid (pure function, so all
// blocks agree bitwise): pass A = per-expert counts cnt_sm[16] (ballot/popc, same
// pattern the old bucket kernel used); pass B = its own tile's 64 bucket entries
// (per-chunk ballot counts -> 1-wave shuffle prefix scan -> emit into lbuck[64]).
// Deterministic sequential-rank order => gemm1's hb layout and gemm2's reads agree.
// Saves 1 kernel + 1 launch boundary (~20us) for ~3us of redundant scan per block.
// GEMM loop itself is the R6/R13-verbatim structure (swizzle + tanh-GELU).
template<int KDIM, int NDIM, bool FIRST>
__global__ __launch_bounds__(256) void moe_gemm(
    const unsigned short* __restrict__ A,
    const unsigned short* __restrict__ Bm,    // [E][NDIM][KDIM] bf16 (pre-transposed)
    const float* __restrict__ bias,           // [E][NDIM]
    const int* __restrict__ eid,              // [NPAIR] expert ids (from head)
    const float* __restrict__ pw,
    unsigned short* __restrict__ hb,          // FIRST: out (bucket-order) / !FIRST: in
    unsigned short* __restrict__ opb)         // !FIRST: out (pair rows)
{
  constexpr int NS  = KDIM / 32;              // K-steps per tile
  constexpr int NBT = NDIM / 128;             // n-tiles per expert
  constexpr int NCH = NPAIR / 64;             // 256 eid chunks

  __shared__ unsigned short As[2*64*32];      //  8 KB (two buffers)
  __shared__ unsigned short Bs[2*128*32];     // 16 KB
  __shared__ int cnt_sm[NE];
  __shared__ int wpart[4][NE];
  __shared__ int chunkpre[NCH];               // chunk counts -> exclusive prefix
  __shared__ int lbuck[64];

  int tid = threadIdx.x;
  int lane = tid & 63, wv = tid >> 6;

  // ---- pass A: per-expert totals (deterministic; replaces cnt[]) ----
  {
    int pc[NE];
    #pragma unroll
    for (int e2=0;e2<NE;e2++) pc[e2]=0;
    for (int c2 = wv; c2 < NCH; c2 += 4){
      int v = eid[c2*64 + lane];
      #pragma unroll
      for (int e2=0;e2<NE;e2++)
        pc[e2] += __popcll(__ballot(v==e2));
    }
    if (lane==0){
      #pragma unroll
      for (int e2=0;e2<NE;e2++) wpart[wv][e2]=pc[e2];
    }
    __syncthreads();
    if (tid < NE) cnt_sm[tid] = wpart[0][tid]+wpart[1][tid]+wpart[2][tid]+wpart[3][tid];
    __syncthreads();
  }

  int ntiles = 0;
  #pragma unroll
  for (int j=0;j<NE;j++) ntiles += ((cnt_sm[j]+63)>>6)*NBT;

  int wm = (wv>>1)*32, wn = (wv&1)*64;
  int lr0 = tid >> 2;
  int c   = tid & 3;
  int sc  = (c ^ ((lr0 >> 1) & 3)) * 8;       // XOR-swizzled LDS col (R6: 0 conflicts)
  int wA  = lr0*32 + sc;
  int fr = lane & 15, fb = lane >> 4;
  int pf8 = (fb ^ ((fr >> 1) & 3)) * 8;
  int fq = (lane>>4)*4;

  // XCD-chunked bijective swizzle: consecutive tiles per XCD share the B n-panel.
  const int t0 = (blockIdx.x & 7)*(gridDim.x >> 3) + (blockIdx.x >> 3);
  for (int t = t0; t < ntiles; t += gridDim.x){
    // ---- tile -> (e, tloc, ebase, ce, itl) via register scan (no arrays) ----
    int e=0, tloc=0, ebase=0, ce=0, itl=1;
    {
      int cum=0, crow=0;
      #pragma unroll
      for (int j=0;j<NE;j++){
        int cj = cnt_sm[j];
        int it = (cj+63)>>6;
        int tj = it * NBT;
        bool in = (t >= cum) & (t < cum+tj);
        if (in){ e=j; tloc=t-cum; ebase=crow; ce=cj; itl=it; }
        cum += tj; crow += cj;
      }
    }
    int i0 = (tloc % itl) * 64;               // i0-fastest ordering
    int n0 = (tloc / itl) * 128;

    // ---- pass B: this tile's bucket window [i0, i0+64) of expert e -> lbuck ----
    __syncthreads();                          // seal prior-iter lbuck readers
    for (int c2 = wv; c2 < NCH; c2 += 4){
      unsigned long long m = __ballot(eid[c2*64 + lane] == e);
      if (lane==0) chunkpre[c2] = __popcll(m);
    }
    if (tid < 64) lbuck[tid] = -1;
    __syncthreads();
    if (wv==0){                               // 1-wave exclusive prefix over 256 counts
      int vals[4];
      #pragma unroll
      for (int j=0;j<4;j++) vals[j] = chunkpre[lane*4+j];
      int lsum = vals[0]+vals[1]+vals[2]+vals[3];
      int pre = lsum;
      #pragma unroll
      for (int off=1; off<64; off<<=1){
        int o = __shfl_up(pre, off, 64);
        if (lane>=off) pre += o;
      }
      pre -= lsum;
      #pragma unroll
      for (int j=0;j<4;j++){ chunkpre[lane*4+j] = pre; pre += vals[j]; }
    }
    __syncthreads();
    for (int c2 = wv; c2 < NCH; c2 += 4){
      int p = c2*64 + lane;
      bool ok = (eid[p] == e);
      unsigned long long m = __ballot(ok);
      int rank = chunkpre[c2] + __popcll(m & ((1ull << lane) - 1ull));
      if (ok && rank >= i0 && rank < i0+64) lbuck[rank - i0] = p;
    }
    __syncthreads();
    if (tid < 64 && lbuck[tid] < 0) lbuck[tid] = lbuck[0];   // tail fill (i0 < ce)
    __syncthreads();

    // ---- A/B global pointers ----
    int posA = i0 + lr0;
    int arow;
    if (FIRST){
      arow = lbuck[lr0] >> 1;                 // gather by token
    } else {
      arow = ebase + posA;                    // sequential bucket-order row
      if (arow > NPAIR-1) arow = NPAIR-1;     // tail guard (stores epilogue-guarded)
    }
    const unsigned short* Ag = A + (size_t)arow*KDIM + c*8;
    const unsigned short* Bg = Bm + (size_t)e*NDIM*KDIM + (size_t)(n0 + lr0)*KDIM + c*8;

    f32x4 acc[2][4];
    #pragma unroll
    for (int a=0;a<2;a++)
      #pragma unroll
      for (int b2=0;b2<4;b2++)
        #pragma unroll
        for (int j=0;j<4;j++) acc[a][b2][j] = 0.f;

    // ---- prologue: tile0 -> buf0; regs = tile1 ----
    float4 ar, br0, br1;
    ar  = *(const float4*)(Ag);
    br0 = *(const float4*)(Bg);
    br1 = *(const float4*)(Bg + (size_t)64*KDIM);
    *(float4*)(As + wA) = ar;
    *(float4*)(Bs + wA) = br0;
    *(float4*)(Bs + wA + 64*32) = br1;
    ar  = *(const float4*)(Ag + 32);
    br0 = *(const float4*)(Bg + 32);
    br1 = *(const float4*)(Bg + (size_t)64*KDIM + 32);
    barrier_lds_only();

    #pragma unroll 2
    for (int k = 0; k < NS; k++){
      const int cur = k & 1, nxt = cur ^ 1;
      float4 na, nb0, nb1;
      bool ld = (k + 2 < NS);
      if (ld){
        na  = *(const float4*)(Ag + (k+2)*32);
        nb0 = *(const float4*)(Bg + (k+2)*32);
        nb1 = *(const float4*)(Bg + (size_t)64*KDIM + (k+2)*32);
      }
      if (k + 1 < NS){
        *(float4*)(As + nxt*2048 + wA) = ar;
        *(float4*)(Bs + nxt*4096 + wA) = br0;
        *(float4*)(Bs + nxt*4096 + wA + 64*32) = br1;
      }
      if (ld){ ar = na; br0 = nb0; br1 = nb1; }

      const unsigned short* Ac = As + cur*2048;
      const unsigned short* Bc = Bs + cur*4096;
      bf16x8 af[2], bfr[4];
      #pragma unroll
      for (int s=0;s<2;s++) af[s]  = *(const bf16x8*)(Ac + (wm + s*16 + fr)*32 + pf8);
      #pragma unroll
      for (int u=0;u<4;u++) bfr[u] = *(const bf16x8*)(Bc + (wn + u*16 + fr)*32 + pf8);
      #pragma unroll
      for (int s=0;s<2;s++)
        #pragma unroll
        for (int u=0;u<4;u++)
          acc[s][u] = __builtin_amdgcn_mfma_f32_16x16x32_bf16(af[s], bfr[u], acc[s][u], 0,0,0);
      barrier_lds_only();   // after this, all waves' LDS ops done -> next tile may restage
    }

    // ---- epilogue: C/D layout col=lane&15, row=(lane>>4)*4+reg [m89-verified] ----
    #pragma unroll
    for (int s=0;s<2;s++){
      #pragma unroll
      for (int i=0;i<4;i++){
        int row = wm + s*16 + fq + i;
        int pos = i0 + row;
        if (pos >= ce) continue;
        #pragma unroll
        for (int u=0;u<4;u++){
          int n = n0 + wn + u*16 + fr;
          float v = acc[s][u][i] + bias[e*NDIM + n];
          if (FIRST){
            // tanh-GELU: g = v * sigmoid(2*0.79788456*(v + 0.044715 v^3))
            float z2 = v*(1.5957691216057308f + 0.0713548162726009f*v*v);
            float g  = __fdividef(v, 1.f + __expf(-z2));
            hb[(size_t)(ebase + pos)*NDIM + n] = f2b(g);
          } else {
            int pair = lbuck[row];
            opb[(size_t)pair*NDIM + n] = f2b(pw[pair]*v);
          }
        }
      }
    }
  }
}

// ---------------- combine: out = x + opb[2t] + opb[2t+1] (coalesced) ----------------
__global__ __launch_bounds__(256) void combine_kernel(const float* __restrict__ x,
                                                      const unsigned short* __restrict__ opb,
                                                      float* __restrict__ out){
  int i = blockIdx.x*256 + threadIdx.x;
  int t  = i >> 7;
  int c4 = i & 127;
  float4 v = ((const float4*)x)[i];
  ushort4 a = ((const ushort4*)opb)[(size_t)(2*t)*128 + c4];
  ushort4 b = ((const ushort4*)opb)[(size_t)(2*t+1)*128 + c4];
  v.x += b2f(a.x) + b2f(b.x);
  v.y += b2f(a.y) + b2f(b.y);
  v.z += b2f(a.z) + b2f(b.z);
  v.w += b2f(a.w) + b2f(b.w);
  ((float4*)out)[i] = v;
}

// ---------------- launch: 4 kernels (bucket folded into the GEMMs) -----------------
extern "C" void kernel_launch(void* const* d_in, const int* in_sizes, int n_in,
                              void* d_out, int out_size, void* d_ws, size_t ws_size,
                              hipStream_t stream)
{
  const float* x  = (const float*)d_in[0];
  const float* Wr = (const float*)d_in[1];
  const float* br = (const float*)d_in[2];
  const float* W1 = (const float*)d_in[3];
  const float* b1 = (const float*)d_in[4];
  const float* W2 = (const float*)d_in[5];
  const float* b2 = (const float*)d_in[6];
  float* out = (float*)d_out;
  char* ws = (char*)d_ws;

  // ws layout (bytes) — same footprint; eid now lives in the dead bucket region
  // (no aliasing anywhere: hb is clean, gemms only READ eid).
  int*            eid    = (int*)(ws + 1024);         // 16384*4 = 65536 (old bucket region)
  float*          pw     = (float*)(ws + 525312);     // 16384*4   = 65536
  unsigned short* xb     = (unsigned short*)(ws + 590848);    // 8192*512*2  = 8388608
  unsigned short* w1t    = (unsigned short*)(ws + 8979456);   // 16*512*1024*2 = 16777216
  unsigned short* w2t    = (unsigned short*)(ws + 25756672);  // 16777216
  unsigned short* hb     = (unsigned short*)(ws + 42533888);  // 16384*1024*2 = 33554432
  // alias (stream-ordered lifetime): opb in w1t region — w1t dead after GEMM1;
  // opb = GEMM2 out, read by combine. 16384*512*2 = 16777216 (exact fit)
  unsigned short* opb    = w1t;

  fused_head<<<6144, 256, 0, stream>>>(x, Wr, br, xb, eid, pw, W1, w1t, W2, w2t);
  moe_gemm<IN_DIM, HID, true ><<<2176, 256, 0, stream>>>(
      xb, w1t, b1, eid, pw, hb, opb);
  moe_gemm<HID, IN_DIM, false><<<1088, 256, 0, stream>>>(
      hb, w2t, b2, eid, pw, hb, opb);
  combine_kernel<<<(T_TOK*IN_DIM/4)/256, 256, 0, stream>>>(x, opb, out);
}

// Round 12
// 231.843 us; speedup vs baseline: 1.8188x; 1.8188x over previous
//
#include <hip/hip_runtime.h>
#include <hip/hip_bf16.h>
#include <math.h>

#define IN_DIM 512
#define HID    1024
#define NE     16
#define T_TOK  8192
#define NPAIR  (T_TOK*2)

typedef __attribute__((ext_vector_type(8))) short bf16x8;
typedef __attribute__((ext_vector_type(8))) unsigned short ushort8;
typedef __attribute__((ext_vector_type(4))) float f32x4;

__device__ __forceinline__ unsigned short f2b(float f){
  unsigned u = __float_as_uint(f);
  u += 0x7FFF + ((u >> 16) & 1);           // round-to-nearest-even
  return (unsigned short)(u >> 16);
}
__device__ __forceinline__ float b2f(unsigned short u){
  return __uint_as_float(((unsigned)u) << 16);
}

// Barrier WITHOUT the vmcnt(0) drain __syncthreads() forces (R6-verified pattern).
__device__ __forceinline__ void barrier_lds_only(){
  asm volatile("s_waitcnt lgkmcnt(0)" ::: "memory");
  __builtin_amdgcn_s_barrier();
}

// ---------------- fused head: router (R21: coalesced-Wr lane transpose) + tconv ----
// router blocks [0,2048): one wave per token. R21 rewires the lane mapping so the
//   Wr load is COALESCED: lane l -> (row-group l>>2, e-quarter l&3); per j-iter the
//   wave loads Wr rows [j*16, j*16+16) as one contiguous 1KB (8 L1 lines vs R13's 64
//   scattered lines/instr — the head's measured 27us excess). x staged in LDS
//   (per-wave region), read back as 4-lane broadcast (conflict-free). Reduction:
//   16 xor-shuffles + 16 gather shuffles (vs 96). Same f32 math and top-2 logic.
// tconv W1: blocks [2048,4096): [E][512][1024] f32 -> [E][1024][512] bf16
// tconv W2: blocks [4096,6144): [E][1024][512] f32 -> [E][512][1024] bf16
// (R17: no global hot atomics; R16: no spin barriers; R19: no atomic epilogues;
//  R20: no per-block recompute of shared pure functions.)
__global__ __launch_bounds__(256) void fused_head(
    const float* __restrict__ x, const float* __restrict__ Wr, const float* __restrict__ br,
    unsigned short* __restrict__ xb, int* __restrict__ eid, float* __restrict__ pw,
    const float* __restrict__ W1, unsigned short* __restrict__ O1,
    const float* __restrict__ W2, unsigned short* __restrict__ O2)
{
  __shared__ __align__(16) char smraw[64*65*4];   // union: tile[64][65] f32 / xs[4][512] f32
  const int b = blockIdx.x;
  const int tid = threadIdx.x;

  if (b < 2048){
    float (*xs)[IN_DIM] = (float(*)[IN_DIM])smraw;   // [4 waves][512]
    int wid = tid >> 6, lane = tid & 63;
    int t = b*4 + wid;
    const float4* xr4 = (const float4*)(x + (size_t)t*IN_DIM);
    ushort4*      xb4 = (ushort4*)(xb + (size_t)t*IN_DIM);

    // ---- load x (coalesced), emit xb, stage into LDS ----
    float4 v0 = xr4[lane];
    float4 v1 = xr4[64 + lane];
    ushort4 o0, o1;
    o0.x=f2b(v0.x); o0.y=f2b(v0.y); o0.z=f2b(v0.z); o0.w=f2b(v0.w);
    o1.x=f2b(v1.x); o1.y=f2b(v1.y); o1.z=f2b(v1.z); o1.w=f2b(v1.w);
    xb4[lane]      = o0;
    xb4[64 + lane] = o1;
    *(float4*)&xs[wid][lane*4]       = v0;
    *(float4*)&xs[wid][256 + lane*4] = v1;
    __syncthreads();

    // ---- logits: lane l owns e-quarter (l&3), row-group (l>>2) ----
    const int qq = lane & 3, rsub = lane >> 2;
    float acc4[4] = {0.f, 0.f, 0.f, 0.f};
    #pragma unroll
    for (int j=0; j<32; j++){
      int row = j*16 + rsub;
      float xv = xs[wid][row];                              // 4-lane broadcast
      float4 w = *(const float4*)&Wr[(size_t)row*NE + qq*4]; // coalesced 1KB/wave
      acc4[0] += xv*w.x; acc4[1] += xv*w.y;
      acc4[2] += xv*w.z; acc4[3] += xv*w.w;
    }
    #pragma unroll
    for (int off=4; off<64; off<<=1){
      #pragma unroll
      for (int i=0;i<4;i++) acc4[i] += __shfl_xor(acc4[i], off, 64);
    }
    // gather 16 logits to every lane (lane q<4 holds e=q*4..q*4+3)
    float lg[16];
    #pragma unroll
    for (int q=0;q<4;q++){
      #pragma unroll
      for (int i=0;i<4;i++) lg[q*4+i] = __shfl(acc4[i], q, 64);
    }
    if (lane==0){
      #pragma unroll
      for (int i=0;i<NE;i++) lg[i] += br[i];
      int e0=0; float l0=lg[0];
      #pragma unroll
      for (int i=1;i<NE;i++) if (lg[i] > l0){ l0=lg[i]; e0=i; }
      int e1=-1; float l1=-3.0e38f;
      #pragma unroll
      for (int i=0;i<NE;i++) if (i!=e0 && lg[i] > l1){ l1=lg[i]; e1=i; }
      float w0 = 1.f/(1.f + __expf(l1 - l0));
      float w1 = 1.f - w0;
      pw[t*2+0] = w0; pw[t*2+1] = w1;
      eid[t*2+0] = e0; eid[t*2+1] = e1;
    }
    return;
  }

  // ---- tconv 64x64 ----
  float (*tile)[65] = (float(*)[65])smraw;
  const float* src; unsigned short* dst; int M, N, m0, n0;
  const int bb = b - 2048;
  if (bb < 2048){
    M = IN_DIM; N = HID;
    int e = bb >> 7, r = bb & 127;            // 8 m-tiles x 16 n-tiles
    n0 = (r & 15)*64; m0 = (r >> 4)*64;
    src = W1 + (size_t)e*M*N; dst = O1 + (size_t)e*M*N;
  } else {
    int b2 = bb - 2048; M = HID; N = IN_DIM;
    int e = b2 >> 7, r = b2 & 127;            // 16 m-tiles x 8 n-tiles
    n0 = (r & 7)*64; m0 = (r >> 3)*64;
    src = W2 + (size_t)e*M*N; dst = O2 + (size_t)e*M*N;
  }
  const int lr = tid >> 4, lc = (tid & 15)*4;
  #pragma unroll
  for (int i=0;i<4;i++)
    *(float4*)&tile[lr + i*16][lc] = *(const float4*)&src[(size_t)(m0 + lr + i*16)*N + n0 + lc];
  __syncthreads();
  const int nr = tid >> 3, mc = (tid & 7)*8;
  #pragma unroll
  for (int p=0;p<2;p++){
    int n = nr + p*32;
    ushort8 o;
    #pragma unroll
    for (int j=0;j<8;j++) o[j] = f2b(tile[mc+j][n]);
    *(ushort8*)&dst[(size_t)(n0 + n)*M + m0 + mc] = o;
  }
}

// ---------------- bucket build: 16 blocks (one per expert), ballot-compact ----------
__global__ __launch_bounds__(1024) void bucket_kernel(const int* __restrict__ eid,
                                                      int* __restrict__ cnt,
                                                      int* __restrict__ bucket){
  int e = blockIdx.x;
  __shared__ int lbase;
  if (threadIdx.x == 0) lbase = 0;
  __syncthreads();
  int lane = threadIdx.x & 63, wid = threadIdx.x >> 6;
  int* be = bucket + e*T_TOK;
  for (int c = wid*64; c < NPAIR; c += 1024){
    int p = c + lane;
    bool ok = (eid[p] == e);
    unsigned long long m = __ballot(ok);
    int rank = __popcll(m & ((1ull << lane) - 1ull));
    int count = __popcll(m);
    int base = 0;
    if (lane == 0) base = atomicAdd(&lbase, count);
    base = __shfl(base, 0, 64);
    if (ok) be[base + rank] = p;
  }
  __syncthreads();
  if (threadIdx.x == 0) cnt[e] = lbase;
}

// ---------------- PERSISTENT grouped GEMM: R6 structure + swizzle + tanhGELU -------
// Grids at tile-count upper bound (gemm1 2176, gemm2 1088): <=1 tile/block.
template<int KDIM, int NDIM, bool FIRST>
__global__ __launch_bounds__(256) void moe_gemm(
    const unsigned short* __restrict__ A,
    const unsigned short* __restrict__ Bm,    // [E][NDIM][KDIM] bf16 (pre-transposed)
    const float* __restrict__ bias,           // [E][NDIM]
    const int* __restrict__ cnt,
    const int* __restrict__ bucket,
    const float* __restrict__ pw,
    unsigned short* __restrict__ hb,          // FIRST: out (bucket-order) / !FIRST: in
    unsigned short* __restrict__ opb)         // !FIRST: out (pair rows)
{
  constexpr int NS  = KDIM / 32;              // K-steps per tile
  constexpr int NBT = NDIM / 128;             // n-tiles per expert

  int ntiles = 0;
  #pragma unroll
  for (int j=0;j<NE;j++) ntiles += ((cnt[j]+63)>>6)*NBT;

  __shared__ unsigned short As[2*64*32];      //  8 KB (two buffers)
  __shared__ unsigned short Bs[2*128*32];     // 16 KB

  int tid = threadIdx.x;
  int lane = tid & 63, wid = tid >> 6;
  int wm = (wid>>1)*32, wn = (wid&1)*64;
  int lr0 = tid >> 2;
  int c   = tid & 3;
  int sc  = (c ^ ((lr0 >> 1) & 3)) * 8;       // XOR-swizzled LDS col (R6: 0 conflicts)
  int wA  = lr0*32 + sc;
  int fr = lane & 15, fb = lane >> 4;
  int pf8 = (fb ^ ((fr >> 1) & 3)) * 8;
  int fq = (lane>>4)*4;

  // XCD-chunked bijective swizzle: consecutive tiles per XCD share the B n-panel.
  const int t0 = (blockIdx.x & 7)*(gridDim.x >> 3) + (blockIdx.x >> 3);
  for (int t = t0; t < ntiles; t += gridDim.x){
    // ---- tile -> (e, tloc, ebase, ce, itl) via register scan (no arrays) ----
    int e=0, tloc=0, ebase=0, ce=0, itl=1;
    {
      int cum=0, crow=0;
      #pragma unroll
      for (int j=0;j<NE;j++){
        int cj = cnt[j];
        int it = (cj+63)>>6;
        int tj = it * NBT;
        bool in = (t >= cum) & (t < cum+tj);
        if (in){ e=j; tloc=t-cum; ebase=crow; ce=cj; itl=it; }
        cum += tj; crow += cj;
      }
    }
    int i0 = (tloc % itl) * 64;               // i0-fastest ordering
    int n0 = (tloc / itl) * 128;

    const int* buck = bucket + e*T_TOK;
    int posA = i0 + lr0;
    int arow;
    if (FIRST){
      int pair = (posA < ce) ? buck[posA] : buck[i0];
      arow = pair >> 1;
    } else {
      arow = ebase + posA;                    // sequential bucket-order row
      if (arow > NPAIR-1) arow = NPAIR-1;     // tail guard (stores epilogue-guarded)
    }
    const unsigned short* Ag = A + (size_t)arow*KDIM + c*8;
    const unsigned short* Bg = Bm + (size_t)e*NDIM*KDIM + (size_t)(n0 + lr0)*KDIM + c*8;

    f32x4 acc[2][4];
    #pragma unroll
    for (int a=0;a<2;a++)
      #pragma unroll
      for (int b2=0;b2<4;b2++)
        #pragma unroll
        for (int j=0;j<4;j++) acc[a][b2][j] = 0.f;

    // ---- prologue: tile0 -> buf0; regs = tile1 ----
    float4 ar, br0, br1;
    ar  = *(const float4*)(Ag);
    br0 = *(const float4*)(Bg);
    br1 = *(const float4*)(Bg + (size_t)64*KDIM);
    *(float4*)(As + wA) = ar;
    *(float4*)(Bs + wA) = br0;
    *(float4*)(Bs + wA + 64*32) = br1;
    ar  = *(const float4*)(Ag + 32);
    br0 = *(const float4*)(Bg + 32);
    br1 = *(const float4*)(Bg + (size_t)64*KDIM + 32);
    barrier_lds_only();

    #pragma unroll 2
    for (int k = 0; k < NS; k++){
      const int cur = k & 1, nxt = cur ^ 1;
      float4 na, nb0, nb1;
      bool ld = (k + 2 < NS);
      if (ld){
        na  = *(const float4*)(Ag + (k+2)*32);
        nb0 = *(const float4*)(Bg + (k+2)*32);
        nb1 = *(const float4*)(Bg + (size_t)64*KDIM + (k+2)*32);
      }
      if (k + 1 < NS){
        *(float4*)(As + nxt*2048 + wA) = ar;
        *(float4*)(Bs + nxt*4096 + wA) = br0;
        *(float4*)(Bs + nxt*4096 + wA + 64*32) = br1;
      }
      if (ld){ ar = na; br0 = nb0; br1 = nb1; }

      const unsigned short* Ac = As + cur*2048;
      const unsigned short* Bc = Bs + cur*4096;
      bf16x8 af[2], bfr[4];
      #pragma unroll
      for (int s=0;s<2;s++) af[s]  = *(const bf16x8*)(Ac + (wm + s*16 + fr)*32 + pf8);
      #pragma unroll
      for (int u=0;u<4;u++) bfr[u] = *(const bf16x8*)(Bc + (wn + u*16 + fr)*32 + pf8);
      #pragma unroll
      for (int s=0;s<2;s++)
        #pragma unroll
        for (int u=0;u<4;u++)
          acc[s][u] = __builtin_amdgcn_mfma_f32_16x16x32_bf16(af[s], bfr[u], acc[s][u], 0,0,0);
      barrier_lds_only();   // after this, all waves' LDS ops done -> next tile may restage
    }

    // ---- epilogue: C/D layout col=lane&15, row=(lane>>4)*4+reg [m89-verified] ----
    #pragma unroll
    for (int s=0;s<2;s++){
      #pragma unroll
      for (int i=0;i<4;i++){
        int row = wm + s*16 + fq + i;
        int pos = i0 + row;
        if (pos >= ce) continue;
        #pragma unroll
        for (int u=0;u<4;u++){
          int n = n0 + wn + u*16 + fr;
          float v = acc[s][u][i] + bias[e*NDIM + n];
          if (FIRST){
            // tanh-GELU: g = v * sigmoid(2*0.79788456*(v + 0.044715 v^3))
            float z2 = v*(1.5957691216057308f + 0.0713548162726009f*v*v);
            float g  = __fdividef(v, 1.f + __expf(-z2));
            hb[(size_t)(ebase + pos)*NDIM + n] = f2b(g);
          } else {
            int pair = buck[pos];
            opb[(size_t)pair*NDIM + n] = f2b(pw[pair]*v);
          }
        }
      }
    }
  }
}

// ---------------- combine: out = x + opb[2t] + opb[2t+1] (coalesced) ----------------
__global__ __launch_bounds__(256) void combine_kernel(const float* __restrict__ x,
                                                      const unsigned short* __restrict__ opb,
                                                      float* __restrict__ out){
  int i = blockIdx.x*256 + threadIdx.x;
  int t  = i >> 7;
  int c4 = i & 127;
  float4 v = ((const float4*)x)[i];
  ushort4 a = ((const ushort4*)opb)[(size_t)(2*t)*128 + c4];
  ushort4 b = ((const ushort4*)opb)[(size_t)(2*t+1)*128 + c4];
  v.x += b2f(a.x) + b2f(b.x);
  v.y += b2f(a.y) + b2f(b.y);
  v.z += b2f(a.z) + b2f(b.z);
  v.w += b2f(a.w) + b2f(b.w);
  ((float4*)out)[i] = v;
}

// ---------------- launch ----------------
extern "C" void kernel_launch(void* const* d_in, const int* in_sizes, int n_in,
                              void* d_out, int out_size, void* d_ws, size_t ws_size,
                              hipStream_t stream)
{
  const float* x  = (const float*)d_in[0];
  const float* Wr = (const float*)d_in[1];
  const float* br = (const float*)d_in[2];
  const float* W1 = (const float*)d_in[3];
  const float* b1 = (const float*)d_in[4];
  const float* W2 = (const float*)d_in[5];
  const float* b2 = (const float*)d_in[6];
  float* out = (float*)d_out;
  char* ws = (char*)d_ws;

  // ws layout (bytes) — identical footprint to the passing layout
  int*            cnt    = (int*)(ws + 0);            // 64 B
  int*            bucket = (int*)(ws + 1024);         // 16*8192*4 = 524288
  float*          pw     = (float*)(ws + 525312);     // 16384*4   = 65536
  unsigned short* xb     = (unsigned short*)(ws + 590848);    // 8192*512*2  = 8388608
  unsigned short* w1t    = (unsigned short*)(ws + 8979456);   // 16*512*1024*2 = 16777216
  unsigned short* w2t    = (unsigned short*)(ws + 25756672);  // 16777216
  unsigned short* hb     = (unsigned short*)(ws + 42533888);  // 16384*1024*2 = 33554432
  // aliases (stream-ordered lifetimes):
  //  eid at hb head: head writes, bucket reads, dead before GEMM1 writes hb
  //  opb in w1t region: w1t dead after GEMM1; opb = GEMM2 out, read by combine
  int*            eid    = (int*)(ws + 42533888);     // 16384*4 = 65536
  unsigned short* opb    = w1t;                       // 16384*512*2 = 16777216 (exact fit)

  fused_head<<<6144, 256, 0, stream>>>(x, Wr, br, xb, eid, pw, W1, w1t, W2, w2t);
  bucket_kernel<<<NE, 1024, 0, stream>>>(eid, cnt, bucket);
  moe_gemm<IN_DIM, HID, true ><<<2176, 256, 0, stream>>>(
      xb, w1t, b1, cnt, bucket, pw, hb, opb);
  moe_gemm<HID, IN_DIM, false><<<1088, 256, 0, stream>>>(
      hb, w2t, b2, cnt, bucket, pw, hb, opb);
  combine_kernel<<<(T_TOK*IN_DIM/4)/256, 256, 0, stream>>>(x, opb, out);
}